// Round 4
// baseline (81.238 us; speedup 1.0000x reference)
//
#include <hip/hip_runtime.h>
#include <math.h>

// Problem shape (fixed by harness setup_inputs): B=8, N=M=4096, D=3, fp32.
#define B_SZ 8
#define N_SZ 4096
#define M_SZ 4096
#define NQ (B_SZ * N_SZ)            // 32768 queries per direction
#define TOT (2 * NQ)                // 65536 total queries

#define THREADS 256
#define QPT 16                      // queries per thread
#define QPB (THREADS * QPT)         // 4096 = N_SZ -> one query tile
#define JTILE 128                   // targets staged in LDS per block
#define NJT (M_SZ / JTILE)          // 32 target tiles (= partial rows)

#define NBLK2 (TOT / 256)           // 256 phase-2 blocks

typedef float f32x2 __attribute__((ext_vector_type(2)));

// ws layout (floats):
//   part[g * TOT + q] : g in [0,NJT) -> 8 MB ; every slot written by phase 1,
//   so the harness 0xAA poison needs no clearing. No atomics anywhere.
//   bsum[NBLK2] at offset NJT*TOT.
//
// score(q,t) = |t|^2/2 - q.t ; argmin_t score == argmin_t |q-t|^2 ;
// partial = min score + |q|^2/2 = min |q-t|^2 / 2 over the tile.
//
// Inner loop packs 2 TARGETS per f32x2 (pairs come straight from LDS, no
// splats), queries pre-splatted into register pairs once. Per (query, 2
// targets): 3 v_pk_fma_f32 + 1 v_min3_f32 = 2 VALU insts per point-pair.
// grid: x = NJT (32), y = B (8), z = dir (2) -> 512 blocks (2/CU).
__global__ __launch_bounds__(THREADS)
void chamfer_partial_kernel(const float* __restrict__ pred,
                            const float* __restrict__ tgt,
                            float* __restrict__ part)
{
    const int b   = blockIdx.y;
    const int dir = blockIdx.z;

    const float* Q;
    const float* Db;
    int qoff;
    if (dir == 0) { Q = pred + (size_t)b * N_SZ * 3; Db = tgt  + (size_t)b * M_SZ * 3; qoff = b * N_SZ; }
    else          { Q = tgt  + (size_t)b * M_SZ * 3; Db = pred + (size_t)b * N_SZ * 3; qoff = NQ + b * M_SZ; }

    const int g = blockIdx.x;

    // Target-pair layout: sA[p] = {x0,x1,y0,y1}, sB[p] = {z0,z1,h0,h1}.
    __shared__ float sA[JTILE * 2];
    __shared__ float sB[JTILE * 2];
    if (threadIdx.x < JTILE) {
        const float* s = Db + (size_t)(g * JTILE + threadIdx.x) * 3;
        float x = s[0], y = s[1], z = s[2];
        float h = 0.5f * (x * x + y * y + z * z);
        const int p = threadIdx.x >> 1, l = threadIdx.x & 1;
        sA[4 * p + l]     = x;
        sA[4 * p + 2 + l] = y;
        sB[4 * p + l]     = z;
        sB[4 * p + 2 + l] = h;
    }
    __syncthreads();

    // 16 queries per thread: negated coords pre-splatted into f32x2 pairs.
    f32x2 qxs[QPT], qys[QPT], qzs[QPT];
    float mn[QPT], q2h[QPT];
#pragma unroll
    for (int k = 0; k < QPT; ++k) {
        const int i = threadIdx.x + k * THREADS;
        float x = Q[i * 3 + 0], y = Q[i * 3 + 1], z = Q[i * 3 + 2];
        qxs[k] = { -x, -x };
        qys[k] = { -y, -y };
        qzs[k] = { -z, -z };
        q2h[k] = 0.5f * (x * x + y * y + z * z);
        mn[k]  = 3.0e38f;
    }

    const float4* A4 = (const float4*)sA;
    const float4* B4 = (const float4*)sB;

    // Per jp: 2 broadcast ds_read_b128 (2 targets), then per query
    // 3 pk_fma + 1 min3.
#pragma unroll 2
    for (int jp = 0; jp < JTILE / 2; ++jp) {
        float4 A = A4[jp];
        float4 B = B4[jp];
        f32x2 tx = { A.x, A.y };
        f32x2 ty = { A.z, A.w };
        f32x2 tz = { B.x, B.y };
        f32x2 th = { B.z, B.w };
#pragma unroll
        for (int k = 0; k < QPT; ++k) {
            f32x2 sc = th + qxs[k] * tx;
            sc += qys[k] * ty;
            sc += qzs[k] * tz;
            mn[k] = fminf(fminf(mn[k], sc.x), sc.y);   // -> v_min3_f32
        }
    }

    // Fold |q|^2/2 -> partial d^2/2; plain coalesced stores.
    float* pg = part + (size_t)g * TOT + qoff;
#pragma unroll
    for (int k = 0; k < QPT; ++k) {
        pg[threadIdx.x + k * THREADS] = mn[k] + q2h[k];
    }
}

// Phase 2: one query per thread; NJT coalesced independent loads; block sum.
__global__ __launch_bounds__(256)
void chamfer_combine_kernel(const float* __restrict__ part,
                            float* __restrict__ bsum)
{
    const int q = blockIdx.x * 256 + threadIdx.x;
    float m = 3.0e38f;
#pragma unroll
    for (int g = 0; g < NJT; ++g) m = fminf(m, part[(size_t)g * TOT + q]);
    float d = sqrtf(2.0f * fmaxf(m, 0.0f));
#pragma unroll
    for (int off = 32; off > 0; off >>= 1) d += __shfl_down(d, off);
    __shared__ float r[4];
    if ((threadIdx.x & 63) == 0) r[threadIdx.x >> 6] = d;
    __syncthreads();
    if (threadIdx.x == 0) bsum[blockIdx.x] = r[0] + r[1] + r[2] + r[3];
}

// Phase 3: one wave sums the 256 block partials.
__global__ __launch_bounds__(64)
void chamfer_final_kernel(const float* __restrict__ bsum,
                          float* __restrict__ out)
{
    float s = 0.0f;
#pragma unroll
    for (int i = 0; i < NBLK2 / 64; ++i) s += bsum[threadIdx.x + i * 64];
#pragma unroll
    for (int off = 32; off > 0; off >>= 1) s += __shfl_down(s, off);
    // loss = mean(min_p2t) + mean(min_t2p) = (sum of all NN dists)/NQ  (N==M)
    if (threadIdx.x == 0) out[0] = s * (1.0f / (float)NQ);
}

extern "C" void kernel_launch(void* const* d_in, const int* in_sizes, int n_in,
                              void* d_out, int out_size, void* d_ws, size_t ws_size,
                              hipStream_t stream) {
    const float* pred = (const float*)d_in[0];  // [B,N,3]
    const float* tgt  = (const float*)d_in[1];  // [B,M,3]
    float* out = (float*)d_out;

    float* part = (float*)d_ws;                 // NJT*TOT floats = 8 MB
    float* bsum = part + (size_t)NJT * TOT;     // NBLK2 floats

    dim3 grid1(NJT, B_SZ, 2);
    chamfer_partial_kernel<<<grid1, THREADS, 0, stream>>>(pred, tgt, part);
    chamfer_combine_kernel<<<NBLK2, 256, 0, stream>>>(part, bsum);
    chamfer_final_kernel<<<1, 64, 0, stream>>>(bsum, out);
}